// Round 10
// baseline (245.545 us; speedup 1.0000x reference)
//
#include <hip/hip_runtime.h>
#include <math.h>
#include <stdint.h>

constexpr int kB = 4;
constexpr int kS = 2048;
constexpr int kD = 1024;
constexpr int kH = 16;
constexpr int kHD = 64;

typedef __bf16 bf16;
typedef __attribute__((ext_vector_type(4))) __bf16 bf16x4;
typedef __attribute__((ext_vector_type(8))) __bf16 bf16x8;
typedef __attribute__((ext_vector_type(4))) float f32x4;

__device__ __forceinline__ f32x4 mfma16x16x32(bf16x8 a, bf16x8 b, f32x4 c) {
    return __builtin_amdgcn_mfma_f32_16x16x32_bf16(a, b, c, 0, 0, 0);
}

#if __has_builtin(__builtin_amdgcn_exp2f)
#define EXP2F(x) __builtin_amdgcn_exp2f(x)
#else
#define EXP2F(x) exp2f(x)
#endif

// async 16B global->LDS. lds base must be wave-uniform (HW adds lane*16);
// the GLOBAL source address is per-lane -> arbitrary gather into linear LDS.
__device__ __forceinline__ void load_lds16(const bf16* g, bf16* lds) {
    __builtin_amdgcn_global_load_lds(
        (const __attribute__((address_space(1))) void*)g,
        (__attribute__((address_space(3))) void*)lds, 16, 0, 0);
}

// ---------------------------------------------------------------------------
// prep_x: fp32 -> bf16 convert of x (8192x1024).
// ---------------------------------------------------------------------------
__global__ __launch_bounds__(256) void prep_x(const float* __restrict__ x,
                                              bf16* __restrict__ xb) {
    size_t i = ((size_t)blockIdx.x * 256 + threadIdx.x) * 8;
    float4 f0 = *(const float4*)(x + i);
    float4 f1 = *(const float4*)(x + i + 4);
    bf16x8 v;
    v[0] = (bf16)f0.x; v[1] = (bf16)f0.y; v[2] = (bf16)f0.z; v[3] = (bf16)f0.w;
    v[4] = (bf16)f1.x; v[5] = (bf16)f1.y; v[6] = (bf16)f1.z; v[7] = (bf16)f1.w;
    *(bf16x8*)(xb + i) = v;
}

// ---------------------------------------------------------------------------
// prep_w: Wt[z*1024 + n][k] = W_z[k][n] * scale_z (bf16, transposed)
// z=0 Wq scaled by 0.125*log2(e) (exp2-domain softmax), 1=Wk, 2=Wv, 3=Wo.
// ---------------------------------------------------------------------------
__global__ __launch_bounds__(256) void prep_w(const float* __restrict__ Wq,
                                              const float* __restrict__ Wk,
                                              const float* __restrict__ Wv,
                                              const float* __restrict__ Wo,
                                              bf16* __restrict__ Wt) {
    __shared__ bf16 t[64 * 72];
    const int z = blockIdx.z;
    const float* W = (z == 0) ? Wq : (z == 1) ? Wk : (z == 2) ? Wv : Wo;
    const float scale = (z == 0) ? 0.18033688011112042f : 1.0f;
    const int k0 = blockIdx.x * 64, n0 = blockIdx.y * 64;
    const int tid = threadIdx.x;
    for (int p = 0; p < 16; ++p) {
        int idx = tid + p * 256;
        int r = idx >> 6, c = idx & 63;
        t[r * 72 + c] = (bf16)(W[(size_t)(k0 + r) * kD + n0 + c] * scale);
    }
    __syncthreads();
    for (int p = 0; p < 16; ++p) {
        int idx = tid + p * 256;
        int r = idx >> 6, c = idx & 63;
        Wt[(size_t)(z * 1024 + n0 + r) * kD + k0 + c] = t[c * 72 + r];
    }
}

// ---------------------------------------------------------------------------
// qkv_gemm v3: BK=32 + 2-phase LDS double-buffer (the attn-v10 discipline).
// R9 counters: 70us, MfmaUtil 30%, Occ 28% -- per K-iter the old
// barrier;stage;barrier;compute structure left the full global-load latency
// (~875cy observed/iter) exposed with only ~2 co-resident blocks to cover it.
// Now stage(t+1) is issued BEFORE compute(t) into buf^1; ONE barrier per
// tile (its implicit vmcnt drain completes stage(t+1) and protects buffer
// reuse).  Load latency hides under the tile's own MFMA+ds_reads.
// LDS 32KB -> 5 blocks/CU cap (grid only has 6/CU of work).
// 128x128 tile, 4 waves 2x2, each 64x64.
// Q,K -> natural [B,S,D] layout (coalesced stores).  V -> [B,H,HD,S].
// ---------------------------------------------------------------------------
__global__ __launch_bounds__(256) void qkv_gemm(
    const bf16* __restrict__ xb, const bf16* __restrict__ Wt,
    bf16* __restrict__ qo, bf16* __restrict__ ko, bf16* __restrict__ vto)
{
    __shared__ bf16 As[2][128 * 32];
    __shared__ bf16 Bs[2][128 * 32];

    const int tid  = threadIdx.x;
    const int wave = tid >> 6;
    const int lane = tid & 63;
    const int quad = lane >> 4;
    const int lr   = lane & 15;
    const int wm   = wave >> 1, wn = wave & 1;

    const int m0 = blockIdx.x * 128;
    const int n0 = blockIdx.y * 128;

    const int sr = tid >> 2, sc = tid & 3;   // staging row (0..63)/16B-chunk; +64 rows per p

    f32x4 acc[4][4];
#pragma unroll
    for (int i = 0; i < 4; ++i)
#pragma unroll
        for (int nt = 0; nt < 4; ++nt) acc[i][nt] = f32x4{0.f, 0.f, 0.f, 0.f};

    // prologue: stage tile 0 into buf 0
#pragma unroll
    for (int p = 0; p < 2; ++p) {
        int r = p * 64 + sr;
        load_lds16(&xb[(size_t)(m0 + r) * kD + sc * 8], &As[0][(p * 256 + wave * 64) * 8]);
        load_lds16(&Wt[(size_t)(n0 + r) * kD + sc * 8], &Bs[0][(p * 256 + wave * 64) * 8]);
    }
    __syncthreads();   // implicit vmcnt drain: tile 0 resident

    int buf = 0;
    for (int k0 = 0; k0 < kD; k0 += 32) {
        // issue next tile's staging into buf^1 (lands under this tile's compute)
        if (k0 + 32 < kD) {
#pragma unroll
            for (int p = 0; p < 2; ++p) {
                int r = p * 64 + sr;
                load_lds16(&xb[(size_t)(m0 + r) * kD + k0 + 32 + sc * 8],
                           &As[buf ^ 1][(p * 256 + wave * 64) * 8]);
                load_lds16(&Wt[(size_t)(n0 + r) * kD + k0 + 32 + sc * 8],
                           &Bs[buf ^ 1][(p * 256 + wave * 64) * 8]);
            }
        }

        bf16x8 a[4], b[4];
#pragma unroll
        for (int i = 0; i < 4; ++i)
            a[i] = *(const bf16x8*)&As[buf][(wm * 64 + i * 16 + lr) * 32 + quad * 8];
#pragma unroll
        for (int nt = 0; nt < 4; ++nt)
            b[nt] = *(const bf16x8*)&Bs[buf][(wn * 64 + nt * 16 + lr) * 32 + quad * 8];
        __builtin_amdgcn_s_setprio(1);
#pragma unroll
        for (int i = 0; i < 4; ++i)
#pragma unroll
            for (int nt = 0; nt < 4; ++nt)
                acc[i][nt] = mfma16x16x32(a[i], b[nt], acc[i][nt]);
        __builtin_amdgcn_s_setprio(0);

        // one barrier per tile: drains vmcnt (stage(t+1) landed) and makes
        // buf safe to overwrite next iteration.
        __syncthreads();
        buf ^= 1;
    }

    const int w_idx = n0 >> 10;               // 0=Q,1=K,2=V (uniform per block)
    if (w_idx < 2) {
        bf16* dst = (w_idx == 0) ? qo : ko;   // [B,S,D] natural layout
#pragma unroll
        for (int i = 0; i < 4; ++i)
#pragma unroll
            for (int nt = 0; nt < 4; ++nt) {
                int n   = n0 + wn * 64 + nt * 16 + lr;
                int col = n & 1023;
#pragma unroll
                for (int j = 0; j < 4; ++j) {
                    int m = m0 + wm * 64 + i * 16 + quad * 4 + j;
                    dst[(size_t)m * kD + col] = (bf16)acc[i][nt][j];
                }
            }
    } else {
        // V transposed: [B,H,HD,S]; j walks s -> bf16x4 stores
#pragma unroll
        for (int i = 0; i < 4; ++i)
#pragma unroll
            for (int nt = 0; nt < 4; ++nt) {
                int n   = n0 + wn * 64 + nt * 16 + lr;
                int col = n & 1023, h = col >> 6, hd = col & 63;
                int mb  = m0 + wm * 64 + i * 16 + quad * 4;
                int b = mb >> 11, s = mb & 2047;
                bf16x4 pk;
#pragma unroll
                for (int j = 0; j < 4; ++j) pk[j] = (bf16)acc[i][nt][j];
                *(bf16x4*)&vto[((size_t)(b * kH + h) * kHD + hd) * kS + s] = pk;
            }
    }
}

// ---------------------------------------------------------------------------
// attn v11 (UNCHANGED from R9): LDS-staged K/V, 4 waves x 16 q-rows over a
// shared 64-row q-block, per-block staging (wave0 K, wave1 V), double-
// buffered, one barrier per tile, XOR chunk-swizzle, swapped QK^T,
// exp2-domain unnormalized softmax, P via per-wave LDS.  2048 jobs,
// heavy-first.
// ---------------------------------------------------------------------------
__global__ __launch_bounds__(256, 3) void attn(
    const bf16* __restrict__ q, const bf16* __restrict__ k,
    const bf16* __restrict__ vt, bf16* __restrict__ ctx)
{
    __shared__ bf16 Ks[2][64 * 64];     // [buf][s][hd]   (chunk-swizzled rows)
    __shared__ bf16 Vs[2][64 * 64];     // [buf][hd][s]   (chunk-swizzled rows)
    __shared__ bf16 Pl[4][16 * 72];     // [wave][qrow*72+key]

    const int tid  = threadIdx.x;
    const int wave = tid >> 6;
    const int lane = tid & 63;
    const int quad = lane >> 4;
    const int lr   = lane & 15;

    const int bh = blockIdx.x;
    const int qb = gridDim.y - 1 - blockIdx.y;   // heavy blocks dispatch first
    const int b  = bh >> 4;
    const int h  = bh & 15;

    // Q,K in [B,S,D]: row = b*kS + s, col = h*64 + hd
    const bf16* qb_p = q  + (size_t)b * kS * kD + h * kHD;
    const bf16* kb_p = k  + (size_t)b * kS * kD + h * kHD;
    const bf16* vt_p = vt + (size_t)bh * kHD * kS; // [hd][s]

    const int T    = qb + 1;              // k-tiles
    const int base = qb * 64 + wave * 16; // first q-row of this wave

    // gather-staging source pattern: instr i, lane l -> row i*8 + (l>>3),
    // 16B chunk (l&7) ^ ((l>>3)&7)  (XOR swizzle; LDS dest stays linear)
    const int grow   = lane >> 3;
    const int gchunk = ((lane & 7) ^ (grow & 7)) * 8;  // element offset

    bf16x8 ones;
#pragma unroll
    for (int i = 0; i < 8; ++i) ones[i] = (bf16)1.0f;

    bf16x8 aq[2];
#pragma unroll
    for (int kk = 0; kk < 2; ++kk)
        aq[kk] = *(const bf16x8*)&qb_p[(size_t)(base + lr) * kD + kk * 32 + quad * 8];

    f32x4 o[4];
    f32x4 lacc = f32x4{0.f, 0.f, 0.f, 0.f};
#pragma unroll
    for (int nt = 0; nt < 4; ++nt) o[nt] = f32x4{0.f, 0.f, 0.f, 0.f};

    bf16* Pw = &Pl[wave][0];

    // prologue: stage tile 0 (wave0: K, wave1: V; waves 2,3 idle here)
    if (wave == 0) {
#pragma unroll
        for (int i = 0; i < 8; ++i)
            load_lds16(kb_p + (size_t)(i * 8 + grow) * kD + gchunk, &Ks[0][i * 512]);
    } else if (wave == 1) {
#pragma unroll
        for (int i = 0; i < 8; ++i)
            load_lds16(vt_p + (size_t)(i * 8 + grow) * kS + gchunk, &Vs[0][i * 512]);
    }
    __syncthreads();

#pragma unroll 1
    for (int kt = 0; kt < T; ++kt) {
        const int k0  = kt * 64;
        const int buf = kt & 1;

        // issue next tile's staging into buf^1 (lands during this tile)
        if (kt + 1 < T) {
            const int nk0 = k0 + 64;
            if (wave == 0) {
#pragma unroll
                for (int i = 0; i < 8; ++i)
                    load_lds16(kb_p + (size_t)(nk0 + i * 8 + grow) * kD + gchunk,
                               &Ks[buf ^ 1][i * 512]);
            } else if (wave == 1) {
#pragma unroll
                for (int i = 0; i < 8; ++i)
                    load_lds16(vt_p + (size_t)(i * 8 + grow) * kS + nk0 + gchunk,
                               &Vs[buf ^ 1][i * 512]);
            }
        }

        // fragments from LDS (swizzled chunk index)
        bf16x8 kf[4][2], vf[4][2];
#pragma unroll
        for (int nt = 0; nt < 4; ++nt)
#pragma unroll
            for (int kk = 0; kk < 2; ++kk) {
                const int sw = ((kk * 4 + quad) ^ (lr & 7)) << 3;
                kf[nt][kk] = *(const bf16x8*)&Ks[buf][(nt * 16 + lr) * 64 + sw];
                vf[nt][kk] = *(const bf16x8*)&Vs[buf][(nt * 16 + lr) * 64 + sw];
            }

        // swapped QK^T: lane holds q-row = base+lr,
        // keys k0 + nt*16 + quad*4 + j (4 consecutive keys per reg)
        f32x4 sg[4];
        __builtin_amdgcn_s_setprio(1);
#pragma unroll
        for (int nt = 0; nt < 4; ++nt) {
            sg[nt] = mfma16x16x32(kf[nt][0], aq[0], f32x4{0.f, 0.f, 0.f, 0.f});
            sg[nt] = mfma16x16x32(kf[nt][1], aq[1], sg[nt]);
        }
        __builtin_amdgcn_s_setprio(0);

        if (kt == T - 1) {
            const int qg = base + lr;
#pragma unroll
            for (int nt = 0; nt < 4; ++nt) {
                bf16x4 pk;
#pragma unroll
                for (int j = 0; j < 4; ++j) {
                    float s = sg[nt][j];
                    s = (k0 + nt * 16 + quad * 4 + j > qg) ? -3.0e38f : s;
                    pk[j] = (bf16)EXP2F(s);
                }
                *(bf16x4*)&Pw[lr * 72 + nt * 16 + quad * 4] = pk;
            }
        } else {
#pragma unroll
            for (int nt = 0; nt < 4; ++nt) {
                bf16x4 pk;
#pragma unroll
                for (int j = 0; j < 4; ++j) pk[j] = (bf16)EXP2F(sg[nt][j]);
                *(bf16x4*)&Pw[lr * 72 + nt * 16 + quad * 4] = pk;
            }
        }

        // O += P @ V ; l += P @ ones   (P read back in A-operand layout)
        __builtin_amdgcn_s_setprio(1);
#pragma unroll
        for (int kk = 0; kk < 2; ++kk) {
            bf16x8 pa = *(const bf16x8*)&Pw[lr * 72 + kk * 32 + quad * 8];
            lacc = mfma16x16x32(pa, ones, lacc);
#pragma unroll
            for (int nt = 0; nt < 4; ++nt)
                o[nt] = mfma16x16x32(pa, vf[nt][kk], o[nt]);
        }
        __builtin_amdgcn_s_setprio(0);

        // barrier: (a) all waves done reading buf before stage(kt+2)
        // overwrites it; (b) implicit vmcnt drain guarantees stage(kt+1)
        // landed before buf^1 is read.
        __syncthreads();
    }

    // ctx [B,S,D] bf16, column h*64+hd; rows base + quad*4 + j
    float inv[4];
#pragma unroll
    for (int j = 0; j < 4; ++j) inv[j] = 1.0f / lacc[j];
#pragma unroll
    for (int nt = 0; nt < 4; ++nt) {
        int hd = nt * 16 + lr;
#pragma unroll
        for (int j = 0; j < 4; ++j) {
            int qg = base + quad * 4 + j;
            ctx[((size_t)(b * kS + qg)) * kD + h * kHD + hd] = (bf16)(o[nt][j] * inv[j]);
        }
    }
}

// ---------------------------------------------------------------------------
// out_gemm v3: same 2-phase double-buffer conversion as qkv_gemm.
// ---------------------------------------------------------------------------
__global__ __launch_bounds__(256) void out_gemm(
    const bf16* __restrict__ ctxb, const bf16* __restrict__ Wto,
    const float* __restrict__ bo, float* __restrict__ out)
{
    __shared__ bf16 As[2][128 * 32];
    __shared__ bf16 Bs[2][128 * 32];

    const int tid  = threadIdx.x;
    const int wave = tid >> 6;
    const int lane = tid & 63;
    const int quad = lane >> 4;
    const int lr   = lane & 15;
    const int wm   = wave >> 1, wn = wave & 1;

    const int m0 = blockIdx.x * 128;
    const int n0 = blockIdx.y * 128;

    const int sr = tid >> 2, sc = tid & 3;

    f32x4 acc[4][4];
#pragma unroll
    for (int i = 0; i < 4; ++i)
#pragma unroll
        for (int nt = 0; nt < 4; ++nt) acc[i][nt] = f32x4{0.f, 0.f, 0.f, 0.f};

    // prologue: stage tile 0 into buf 0
#pragma unroll
    for (int p = 0; p < 2; ++p) {
        int r = p * 64 + sr;
        load_lds16(&ctxb[(size_t)(m0 + r) * kD + sc * 8], &As[0][(p * 256 + wave * 64) * 8]);
        load_lds16(&Wto[(size_t)(n0 + r) * kD + sc * 8], &Bs[0][(p * 256 + wave * 64) * 8]);
    }
    __syncthreads();

    int buf = 0;
    for (int k0 = 0; k0 < kD; k0 += 32) {
        if (k0 + 32 < kD) {
#pragma unroll
            for (int p = 0; p < 2; ++p) {
                int r = p * 64 + sr;
                load_lds16(&ctxb[(size_t)(m0 + r) * kD + k0 + 32 + sc * 8],
                           &As[buf ^ 1][(p * 256 + wave * 64) * 8]);
                load_lds16(&Wto[(size_t)(n0 + r) * kD + k0 + 32 + sc * 8],
                           &Bs[buf ^ 1][(p * 256 + wave * 64) * 8]);
            }
        }

        bf16x8 a[4], b[4];
#pragma unroll
        for (int i = 0; i < 4; ++i)
            a[i] = *(const bf16x8*)&As[buf][(wm * 64 + i * 16 + lr) * 32 + quad * 8];
#pragma unroll
        for (int nt = 0; nt < 4; ++nt)
            b[nt] = *(const bf16x8*)&Bs[buf][(wn * 64 + nt * 16 + lr) * 32 + quad * 8];
        __builtin_amdgcn_s_setprio(1);
#pragma unroll
        for (int i = 0; i < 4; ++i)
#pragma unroll
            for (int nt = 0; nt < 4; ++nt)
                acc[i][nt] = mfma16x16x32(a[i], b[nt], acc[i][nt]);
        __builtin_amdgcn_s_setprio(0);

        __syncthreads();
        buf ^= 1;
    }

#pragma unroll
    for (int nt = 0; nt < 4; ++nt) {
        int n = n0 + wn * 64 + nt * 16 + lr;
        float bias = bo[n];
#pragma unroll
        for (int i = 0; i < 4; ++i)
#pragma unroll
            for (int j = 0; j < 4; ++j) {
                int m = m0 + wm * 64 + i * 16 + quad * 4 + j;
                out[(size_t)m * kD + n] = acc[i][nt][j] + bias;
            }
    }
}

// ---------------------------------------------------------------------------
extern "C" void kernel_launch(void* const* d_in, const int* in_sizes, int n_in,
                              void* d_out, int out_size, void* d_ws, size_t ws_size,
                              hipStream_t stream) {
    const float* x  = (const float*)d_in[0];
    const float* Wq = (const float*)d_in[1];
    const float* Wk = (const float*)d_in[2];
    const float* Wv = (const float*)d_in[3];
    const float* Wo = (const float*)d_in[4];
    const float* bo = (const float*)d_in[5];
    float* out = (float*)d_out;

    const size_t n_x   = (size_t)kB * kS * kD;       // 8,388,608
    const size_t n_w   = (size_t)4 * kD * kD;        // 4,194,304
    const size_t n_mat = (size_t)kB * kH * kS * kHD; // 8,388,608

    bf16* xb  = (bf16*)d_ws;        // 16 MB (reused as ctx after qkv_gemm)
    bf16* Wt  = xb + n_x;           // 8 MB
    bf16* Qm  = Wt + n_w;           // 16 MB [B,S,D]
    bf16* Km  = Qm + n_mat;         // 16 MB [B,S,D]
    bf16* Vt  = Km + n_mat;         // 16 MB [B,H,HD,S]
    bf16* ctx = xb;                 // reuse: x dead after qkv_gemm

    prep_x<<<dim3((int)(n_x / (256 * 8))), dim3(256), 0, stream>>>(x, xb);
    prep_w<<<dim3(16, 16, 4), dim3(256), 0, stream>>>(Wq, Wk, Wv, Wo, Wt);
    qkv_gemm<<<dim3(8192 / 128, 3072 / 128), dim3(256), 0, stream>>>(xb, Wt, Qm, Km, Vt);
    attn<<<dim3(kB * kH, 32), dim3(256), 0, stream>>>(Qm, Km, Vt, ctx);
    out_gemm<<<dim3(8192 / 128, 1024 / 128), dim3(256), 0, stream>>>(
        ctx, Wt + (size_t)3 * kD * kD, bo, out);
}

// Round 11
// 243.251 us; speedup vs baseline: 1.0094x; 1.0094x over previous
//
#include <hip/hip_runtime.h>
#include <math.h>
#include <stdint.h>

constexpr int kB = 4;
constexpr int kS = 2048;
constexpr int kD = 1024;
constexpr int kH = 16;
constexpr int kHD = 64;

typedef __bf16 bf16;
typedef __attribute__((ext_vector_type(4))) __bf16 bf16x4;
typedef __attribute__((ext_vector_type(8))) __bf16 bf16x8;
typedef __attribute__((ext_vector_type(4))) float f32x4;

__device__ __forceinline__ f32x4 mfma16x16x32(bf16x8 a, bf16x8 b, f32x4 c) {
    return __builtin_amdgcn_mfma_f32_16x16x32_bf16(a, b, c, 0, 0, 0);
}

#if __has_builtin(__builtin_amdgcn_exp2f)
#define EXP2F(x) __builtin_amdgcn_exp2f(x)
#else
#define EXP2F(x) exp2f(x)
#endif

// async 16B global->LDS. lds base must be wave-uniform (HW adds lane*16);
// the GLOBAL source address is per-lane -> arbitrary gather into linear LDS.
__device__ __forceinline__ void load_lds16(const bf16* g, bf16* lds) {
    __builtin_amdgcn_global_load_lds(
        (const __attribute__((address_space(1))) void*)g,
        (__attribute__((address_space(3))) void*)lds, 16, 0, 0);
}

// ---------------------------------------------------------------------------
// prep_x: fp32 -> bf16 convert of x (8192x1024).
// ---------------------------------------------------------------------------
__global__ __launch_bounds__(256) void prep_x(const float* __restrict__ x,
                                              bf16* __restrict__ xb) {
    size_t i = ((size_t)blockIdx.x * 256 + threadIdx.x) * 8;
    float4 f0 = *(const float4*)(x + i);
    float4 f1 = *(const float4*)(x + i + 4);
    bf16x8 v;
    v[0] = (bf16)f0.x; v[1] = (bf16)f0.y; v[2] = (bf16)f0.z; v[3] = (bf16)f0.w;
    v[4] = (bf16)f1.x; v[5] = (bf16)f1.y; v[6] = (bf16)f1.z; v[7] = (bf16)f1.w;
    *(bf16x8*)(xb + i) = v;
}

// ---------------------------------------------------------------------------
// prep_w: Wt[z*1024 + n][k] = W_z[k][n] * scale_z (bf16, transposed)
// z=0 Wq scaled by 0.125*log2(e) (exp2-domain softmax), 1=Wk, 2=Wv, 3=Wo.
// ---------------------------------------------------------------------------
__global__ __launch_bounds__(256) void prep_w(const float* __restrict__ Wq,
                                              const float* __restrict__ Wk,
                                              const float* __restrict__ Wv,
                                              const float* __restrict__ Wo,
                                              bf16* __restrict__ Wt) {
    __shared__ bf16 t[64 * 72];
    const int z = blockIdx.z;
    const float* W = (z == 0) ? Wq : (z == 1) ? Wk : (z == 2) ? Wv : Wo;
    const float scale = (z == 0) ? 0.18033688011112042f : 1.0f;
    const int k0 = blockIdx.x * 64, n0 = blockIdx.y * 64;
    const int tid = threadIdx.x;
    for (int p = 0; p < 16; ++p) {
        int idx = tid + p * 256;
        int r = idx >> 6, c = idx & 63;
        t[r * 72 + c] = (bf16)(W[(size_t)(k0 + r) * kD + n0 + c] * scale);
    }
    __syncthreads();
    for (int p = 0; p < 16; ++p) {
        int idx = tid + p * 256;
        int r = idx >> 6, c = idx & 63;
        Wt[(size_t)(z * 1024 + n0 + r) * kD + k0 + c] = t[c * 72 + r];
    }
}

// ---------------------------------------------------------------------------
// qkv_gemm v4: 8-phase 256x256 schedule (T3+T4+T5, plain-HIP port of the
// m201 template).  R10 analysis: qkv is ~73% DS-pipe-bound; DS bytes/MAC is
// set by the WAVE tile, so the fix is wave tile 128x64 (2M x 4N, 8 waves) =
// -33% DS/MAC, plus counted-vmcnt pipelining.
//   BM=BN=256, BK=64, LDS 128KB (2 dbuf x [256x64] x A,B), 1 block/CU.
//   K-iter = 2 K-tiles (buf0 even, buf1 odd), 8 phases; per phase:
//     {4x ds_read a-frags (+8x b-frags at tile-phase 0); stage 1 half-tile
//      (2x global_load_lds, XOR-chunk-preswizzled source, linear LDS dest);
//      s_barrier; lgkmcnt(0)+sched_barrier; 16 MFMA (setprio-wrapped);
//      [vmcnt(4) at phases 4,8 -- never 0]; s_barrier}.
//   Stage slots: ph1-2 A(t1)->buf1, ph3-4 B(t0+2)->buf0, ph5-6 A(t0+2)->buf0,
//   ph7-8 B(t1+2)->buf1.  Every restage is >=1 phase after the region's last
//   read (WAR-safe via phase barriers); vmcnt(4)+barrier gates consumers.
// Q,K -> natural [B,S,D] layout.  V -> [B,H,HD,S].
// ---------------------------------------------------------------------------
__global__ __launch_bounds__(512) void qkv_gemm(
    const bf16* __restrict__ xb, const bf16* __restrict__ Wt,
    bf16* __restrict__ qo, bf16* __restrict__ ko, bf16* __restrict__ vto)
{
    __shared__ bf16 As[2][256 * 64];
    __shared__ bf16 Bs[2][256 * 64];

    const int tid  = threadIdx.x;
    const int wave = tid >> 6;
    const int lane = tid & 63;
    const int quad = lane >> 4;
    const int lr   = lane & 15;
    const int wm   = wave >> 2;          // 0..1
    const int wn   = wave & 3;           // 0..3

    const int m0 = blockIdx.x * 256;
    const int n0 = blockIdx.y * 256;

    // staging: thread t -> row (t>>3) within a 64-row round, slot t&7;
    // source chunk = slot ^ (row&7)  (XOR swizzle; LDS dest linear)
    const int srow   = tid >> 3;                               // 0..63
    const int schunk = ((tid & 7) ^ ((tid >> 3) & 7)) * 8;     // elem offset

// stage half h (128 rows) of K-tile kt into buffer b: 2 loads/wave
#define STG_A(b_, kt_, h_) do {                                                \
    const int ktc = (kt_) < 16 ? (kt_) : 15;                                   \
    const size_t kc = (size_t)ktc * 64 + schunk;                               \
    load_lds16(&xb[(size_t)(m0 + (h_)*128 +      srow) * kD + kc],             \
               &As[b_][((h_)*128 +      wave * 8) * 64]);                      \
    load_lds16(&xb[(size_t)(m0 + (h_)*128 + 64 + srow) * kD + kc],             \
               &As[b_][((h_)*128 + 64 + wave * 8) * 64]);                      \
  } while (0)
#define STG_B(b_, kt_, h_) do {                                                \
    const int ktc = (kt_) < 16 ? (kt_) : 15;                                   \
    const size_t kc = (size_t)ktc * 64 + schunk;                               \
    load_lds16(&Wt[(size_t)(n0 + (h_)*128 +      srow) * kD + kc],             \
               &Bs[b_][((h_)*128 +      wave * 8) * 64]);                      \
    load_lds16(&Wt[(size_t)(n0 + (h_)*128 + 64 + srow) * kD + kc],             \
               &Bs[b_][((h_)*128 + 64 + wave * 8) * 64]);                      \
  } while (0)

#define READ_A(B_, I_, KK_) \
    (*(const bf16x8*)&As[B_][(wm * 128 + (I_)*16 + lr) * 64 + ((((KK_)*4 + quad) ^ (lr & 7)) << 3)])
#define READ_B(B_, NT_, KK_) \
    (*(const bf16x8*)&Bs[B_][(wn * 64 + (NT_)*16 + lr) * 64 + ((((KK_)*4 + quad) ^ (lr & 7)) << 3)])

#define PH(B_, I0_, RB_, STMT, DOVM) do {                                      \
    bf16x8 a00 = READ_A(B_, I0_, 0);                                           \
    bf16x8 a01 = READ_A(B_, I0_, 1);                                           \
    bf16x8 a10 = READ_A(B_, (I0_) + 1, 0);                                     \
    bf16x8 a11 = READ_A(B_, (I0_) + 1, 1);                                     \
    if (RB_) {                                                                 \
        _Pragma("unroll")                                                      \
        for (int nt = 0; nt < 4; ++nt) {                                       \
            br[nt][0] = READ_B(B_, nt, 0);                                     \
            br[nt][1] = READ_B(B_, nt, 1);                                     \
        }                                                                      \
    }                                                                          \
    STMT;                                                                      \
    __builtin_amdgcn_s_barrier();                                              \
    asm volatile("s_waitcnt lgkmcnt(0)" ::: "memory");                         \
    __builtin_amdgcn_sched_barrier(0);                                         \
    __builtin_amdgcn_s_setprio(1);                                             \
    _Pragma("unroll")                                                          \
    for (int nt = 0; nt < 4; ++nt) {                                           \
        acc[I0_][nt]       = mfma16x16x32(a00, br[nt][0], acc[I0_][nt]);       \
        acc[I0_][nt]       = mfma16x16x32(a01, br[nt][1], acc[I0_][nt]);       \
        acc[(I0_) + 1][nt] = mfma16x16x32(a10, br[nt][0], acc[(I0_) + 1][nt]); \
        acc[(I0_) + 1][nt] = mfma16x16x32(a11, br[nt][1], acc[(I0_) + 1][nt]); \
    }                                                                          \
    __builtin_amdgcn_s_setprio(0);                                             \
    if (DOVM) {                                                                \
        asm volatile("s_waitcnt vmcnt(4)" ::: "memory");                       \
        __builtin_amdgcn_sched_barrier(0);                                     \
    }                                                                          \
    __builtin_amdgcn_s_barrier();                                              \
  } while (0)

    f32x4 acc[8][4];
#pragma unroll
    for (int i = 0; i < 8; ++i)
#pragma unroll
        for (int nt = 0; nt < 4; ++nt) acc[i][nt] = f32x4{0.f, 0.f, 0.f, 0.f};

    bf16x8 br[4][2];

    // prologue: B(0), A(0), B(1) staged (12 loads/wave); gate tile 0.
    STG_B(0, 0, 0); STG_B(0, 0, 1);
    STG_A(0, 0, 0); STG_A(0, 0, 1);
    STG_B(1, 1, 0); STG_B(1, 1, 1);
    asm volatile("s_waitcnt vmcnt(4)" ::: "memory");
    __builtin_amdgcn_sched_barrier(0);
    __builtin_amdgcn_s_barrier();

#pragma unroll 1
    for (int j = 0; j < 8; ++j) {
        const int t1  = 2 * j + 1;
        const int tn0 = 2 * j + 2;
        const int tn1 = 2 * j + 3;
        // tile t0 (buf0), phases 1-4
        PH(0, 0, 1, STG_A(1, t1, 0),  0);
        PH(0, 2, 0, STG_A(1, t1, 1),  0);
        PH(0, 4, 0, STG_B(0, tn0, 0), 0);
        PH(0, 6, 0, STG_B(0, tn0, 1), 1);   // vmcnt(4): A(t1)+B(t1) landed
        // tile t1 (buf1), phases 5-8
        PH(1, 0, 1, STG_A(0, tn0, 0), 0);
        PH(1, 2, 0, STG_A(0, tn0, 1), 0);
        PH(1, 4, 0, STG_B(1, tn1, 0), 0);
        PH(1, 6, 0, STG_B(1, tn1, 1), 1);   // vmcnt(4): A,B(tn0) landed
    }

    const int w_idx = n0 >> 10;               // 0=Q,1=K,2=V (uniform per block)
    if (w_idx < 2) {
        bf16* dst = (w_idx == 0) ? qo : ko;   // [B,S,D] natural layout
#pragma unroll
        for (int i = 0; i < 8; ++i)
#pragma unroll
            for (int nt = 0; nt < 4; ++nt) {
                int n   = n0 + wn * 64 + nt * 16 + lr;
                int col = n & 1023;
#pragma unroll
                for (int jj = 0; jj < 4; ++jj) {
                    int m = m0 + wm * 128 + i * 16 + quad * 4 + jj;
                    dst[(size_t)m * kD + col] = (bf16)acc[i][nt][jj];
                }
            }
    } else {
        // V transposed: [B,H,HD,S]; jj walks s -> bf16x4 stores
#pragma unroll
        for (int i = 0; i < 8; ++i)
#pragma unroll
            for (int nt = 0; nt < 4; ++nt) {
                int n   = n0 + wn * 64 + nt * 16 + lr;
                int col = n & 1023, h = col >> 6, hd = col & 63;
                int mb  = m0 + wm * 128 + i * 16 + quad * 4;
                int b = mb >> 11, s = mb & 2047;
                bf16x4 pk;
#pragma unroll
                for (int jj = 0; jj < 4; ++jj) pk[jj] = (bf16)acc[i][nt][jj];
                *(bf16x4*)&vto[((size_t)(b * kH + h) * kHD + hd) * kS + s] = pk;
            }
    }
#undef PH
#undef READ_A
#undef READ_B
#undef STG_A
#undef STG_B
}

// ---------------------------------------------------------------------------
// attn v11 (UNCHANGED from R9, best measured): LDS-staged K/V, 4 waves x 16
// q-rows over a shared 64-row q-block, per-block staging (wave0 K, wave1 V),
// double-buffered, one barrier per tile, XOR chunk-swizzle, swapped QK^T,
// exp2-domain unnormalized softmax, P via per-wave LDS.  2048 jobs,
// heavy-first.
// ---------------------------------------------------------------------------
__global__ __launch_bounds__(256, 3) void attn(
    const bf16* __restrict__ q, const bf16* __restrict__ k,
    const bf16* __restrict__ vt, bf16* __restrict__ ctx)
{
    __shared__ bf16 Ks[2][64 * 64];     // [buf][s][hd]   (chunk-swizzled rows)
    __shared__ bf16 Vs[2][64 * 64];     // [buf][hd][s]   (chunk-swizzled rows)
    __shared__ bf16 Pl[4][16 * 72];     // [wave][qrow*72+key]

    const int tid  = threadIdx.x;
    const int wave = tid >> 6;
    const int lane = tid & 63;
    const int quad = lane >> 4;
    const int lr   = lane & 15;

    const int bh = blockIdx.x;
    const int qb = gridDim.y - 1 - blockIdx.y;   // heavy blocks dispatch first
    const int b  = bh >> 4;
    const int h  = bh & 15;

    // Q,K in [B,S,D]: row = b*kS + s, col = h*64 + hd
    const bf16* qb_p = q  + (size_t)b * kS * kD + h * kHD;
    const bf16* kb_p = k  + (size_t)b * kS * kD + h * kHD;
    const bf16* vt_p = vt + (size_t)bh * kHD * kS; // [hd][s]

    const int T    = qb + 1;              // k-tiles
    const int base = qb * 64 + wave * 16; // first q-row of this wave

    // gather-staging source pattern: instr i, lane l -> row i*8 + (l>>3),
    // 16B chunk (l&7) ^ ((l>>3)&7)  (XOR swizzle; LDS dest stays linear)
    const int grow   = lane >> 3;
    const int gchunk = ((lane & 7) ^ (grow & 7)) * 8;  // element offset

    bf16x8 ones;
#pragma unroll
    for (int i = 0; i < 8; ++i) ones[i] = (bf16)1.0f;

    bf16x8 aq[2];
#pragma unroll
    for (int kk = 0; kk < 2; ++kk)
        aq[kk] = *(const bf16x8*)&qb_p[(size_t)(base + lr) * kD + kk * 32 + quad * 8];

    f32x4 o[4];
    f32x4 lacc = f32x4{0.f, 0.f, 0.f, 0.f};
#pragma unroll
    for (int nt = 0; nt < 4; ++nt) o[nt] = f32x4{0.f, 0.f, 0.f, 0.f};

    bf16* Pw = &Pl[wave][0];

    // prologue: stage tile 0 (wave0: K, wave1: V; waves 2,3 idle here)
    if (wave == 0) {
#pragma unroll
        for (int i = 0; i < 8; ++i)
            load_lds16(kb_p + (size_t)(i * 8 + grow) * kD + gchunk, &Ks[0][i * 512]);
    } else if (wave == 1) {
#pragma unroll
        for (int i = 0; i < 8; ++i)
            load_lds16(vt_p + (size_t)(i * 8 + grow) * kS + gchunk, &Vs[0][i * 512]);
    }
    __syncthreads();

#pragma unroll 1
    for (int kt = 0; kt < T; ++kt) {
        const int k0  = kt * 64;
        const int buf = kt & 1;

        // issue next tile's staging into buf^1 (lands during this tile)
        if (kt + 1 < T) {
            const int nk0 = k0 + 64;
            if (wave == 0) {
#pragma unroll
                for (int i = 0; i < 8; ++i)
                    load_lds16(kb_p + (size_t)(nk0 + i * 8 + grow) * kD + gchunk,
                               &Ks[buf ^ 1][i * 512]);
            } else if (wave == 1) {
#pragma unroll
                for (int i = 0; i < 8; ++i)
                    load_lds16(vt_p + (size_t)(i * 8 + grow) * kS + nk0 + gchunk,
                               &Vs[buf ^ 1][i * 512]);
            }
        }

        // fragments from LDS (swizzled chunk index)
        bf16x8 kf[4][2], vf[4][2];
#pragma unroll
        for (int nt = 0; nt < 4; ++nt)
#pragma unroll
            for (int kk = 0; kk < 2; ++kk) {
                const int sw = ((kk * 4 + quad) ^ (lr & 7)) << 3;
                kf[nt][kk] = *(const bf16x8*)&Ks[buf][(nt * 16 + lr) * 64 + sw];
                vf[nt][kk] = *(const bf16x8*)&Vs[buf][(nt * 16 + lr) * 64 + sw];
            }

        // swapped QK^T: lane holds q-row = base+lr,
        // keys k0 + nt*16 + quad*4 + j (4 consecutive keys per reg)
        f32x4 sg[4];
        __builtin_amdgcn_s_setprio(1);
#pragma unroll
        for (int nt = 0; nt < 4; ++nt) {
            sg[nt] = mfma16x16x32(kf[nt][0], aq[0], f32x4{0.f, 0.f, 0.f, 0.f});
            sg[nt] = mfma16x16x32(kf[nt][1], aq[1], sg[nt]);
        }
        __builtin_amdgcn_s_setprio(0);

        if (kt == T - 1) {
            const int qg = base + lr;
#pragma unroll
            for (int nt = 0; nt < 4; ++nt) {
                bf16x4 pk;
#pragma unroll
                for (int j = 0; j < 4; ++j) {
                    float s = sg[nt][j];
                    s = (k0 + nt * 16 + quad * 4 + j > qg) ? -3.0e38f : s;
                    pk[j] = (bf16)EXP2F(s);
                }
                *(bf16x4*)&Pw[lr * 72 + nt * 16 + quad * 4] = pk;
            }
        } else {
#pragma unroll
            for (int nt = 0; nt < 4; ++nt) {
                bf16x4 pk;
#pragma unroll
                for (int j = 0; j < 4; ++j) pk[j] = (bf16)EXP2F(sg[nt][j]);
                *(bf16x4*)&Pw[lr * 72 + nt * 16 + quad * 4] = pk;
            }
        }

        // O += P @ V ; l += P @ ones   (P read back in A-operand layout)
        __builtin_amdgcn_s_setprio(1);
#pragma unroll
        for (int kk = 0; kk < 2; ++kk) {
            bf16x8 pa = *(const bf16x8*)&Pw[lr * 72 + kk * 32 + quad * 8];
            lacc = mfma16x16x32(pa, ones, lacc);
#pragma unroll
            for (int nt = 0; nt < 4; ++nt)
                o[nt] = mfma16x16x32(pa, vf[nt][kk], o[nt]);
        }
        __builtin_amdgcn_s_setprio(0);

        // barrier: (a) all waves done reading buf before stage(kt+2)
        // overwrites it; (b) implicit vmcnt drain guarantees stage(kt+1)
        // landed before buf^1 is read.
        __syncthreads();
    }

    // ctx [B,S,D] bf16, column h*64+hd; rows base + quad*4 + j
    float inv[4];
#pragma unroll
    for (int j = 0; j < 4; ++j) inv[j] = 1.0f / lacc[j];
#pragma unroll
    for (int nt = 0; nt < 4; ++nt) {
        int hd = nt * 16 + lr;
#pragma unroll
        for (int j = 0; j < 4; ++j) {
            int qg = base + quad * 4 + j;
            ctx[((size_t)(b * kS + qg)) * kD + h * kHD + hd] = (bf16)(o[nt][j] * inv[j]);
        }
    }
}

// ---------------------------------------------------------------------------
// out_gemm (R9 form, best measured): out = ctx @ Wo + bo (fp32), BK=32,
// 128x128 tile, 16KB LDS -> high residency.
// ---------------------------------------------------------------------------
__global__ __launch_bounds__(256) void out_gemm(
    const bf16* __restrict__ ctxb, const bf16* __restrict__ Wto,
    const float* __restrict__ bo, float* __restrict__ out)
{
    __shared__ bf16 As[128 * 32];
    __shared__ bf16 Bs[128 * 32];

    const int tid  = threadIdx.x;
    const int wave = tid >> 6;
    const int lane = tid & 63;
    const int quad = lane >> 4;
    const int lr   = lane & 15;
    const int wm   = wave >> 1, wn = wave & 1;

    const int m0 = blockIdx.x * 128;
    const int n0 = blockIdx.y * 128;

    const int sr = tid >> 2, sc = tid & 3;

    f32x4 acc[4][4];
#pragma unroll
    for (int i = 0; i < 4; ++i)
#pragma unroll
        for (int nt = 0; nt < 4; ++nt) acc[i][nt] = f32x4{0.f, 0.f, 0.f, 0.f};

    for (int k0 = 0; k0 < kD; k0 += 32) {
        __syncthreads();
#pragma unroll
        for (int p = 0; p < 2; ++p) {
            int r = p * 64 + sr;
            load_lds16(&ctxb[(size_t)(m0 + r) * kD + k0 + sc * 8],
                       &As[(p * 256 + wave * 64) * 8]);
            load_lds16(&Wto[(size_t)(n0 + r) * kD + k0 + sc * 8],
                       &Bs[(p * 256 + wave * 64) * 8]);
        }
        __syncthreads();
        bf16x8 a[4], b[4];
#pragma unroll
        for (int i = 0; i < 4; ++i)
            a[i] = *(const bf16x8*)&As[(wm * 64 + i * 16 + lr) * 32 + quad * 8];
#pragma unroll
        for (int nt = 0; nt < 4; ++nt)
            b[nt] = *(const bf16x8*)&Bs[(wn * 64 + nt * 16 + lr) * 32 + quad * 8];
#pragma unroll
        for (int i = 0; i < 4; ++i)
#pragma unroll
            for (int nt = 0; nt < 4; ++nt)
                acc[i][nt] = mfma16x16x32(a[i], b[nt], acc[i][nt]);
    }

#pragma unroll
    for (int nt = 0; nt < 4; ++nt) {
        int n = n0 + wn * 64 + nt * 16 + lr;
        float bias = bo[n];
#pragma unroll
        for (int i = 0; i < 4; ++i)
#pragma unroll
            for (int j = 0; j < 4; ++j) {
                int m = m0 + wm * 64 + i * 16 + quad * 4 + j;
                out[(size_t)m * kD + n] = acc[i][nt][j] + bias;
            }
    }
}

// ---------------------------------------------------------------------------
extern "C" void kernel_launch(void* const* d_in, const int* in_sizes, int n_in,
                              void* d_out, int out_size, void* d_ws, size_t ws_size,
                              hipStream_t stream) {
    const float* x  = (const float*)d_in[0];
    const float* Wq = (const float*)d_in[1];
    const float* Wk = (const float*)d_in[2];
    const float* Wv = (const float*)d_in[3];
    const float* Wo = (const float*)d_in[4];
    const float* bo = (const float*)d_in[5];
    float* out = (float*)d_out;

    const size_t n_x   = (size_t)kB * kS * kD;       // 8,388,608
    const size_t n_w   = (size_t)4 * kD * kD;        // 4,194,304
    const size_t n_mat = (size_t)kB * kH * kS * kHD; // 8,388,608

    bf16* xb  = (bf16*)d_ws;        // 16 MB (reused as ctx after qkv_gemm)
    bf16* Wt  = xb + n_x;           // 8 MB
    bf16* Qm  = Wt + n_w;           // 16 MB [B,S,D]
    bf16* Km  = Qm + n_mat;         // 16 MB [B,S,D]
    bf16* Vt  = Km + n_mat;         // 16 MB [B,H,HD,S]
    bf16* ctx = xb;                 // reuse: x dead after qkv_gemm

    prep_x<<<dim3((int)(n_x / (256 * 8))), dim3(256), 0, stream>>>(x, xb);
    prep_w<<<dim3(16, 16, 4), dim3(256), 0, stream>>>(Wq, Wk, Wv, Wo, Wt);
    qkv_gemm<<<dim3(8192 / 256, 3072 / 256), dim3(512), 0, stream>>>(xb, Wt, Qm, Km, Vt);
    attn<<<dim3(kB * kH, 32), dim3(256), 0, stream>>>(Qm, Km, Vt, ctx);
    out_gemm<<<dim3(8192 / 128, 1024 / 128), dim3(256), 0, stream>>>(
        ctx, Wt + (size_t)3 * kD * kD, bo, out);
}